// Round 1
// baseline (496.124 us; speedup 1.0000x reference)
//
#include <hip/hip_runtime.h>

#define DIM 4096
#define BM 128
#define BN 128
#define BK 32

typedef _Float16 half8 __attribute__((ext_vector_type(8)));
typedef _Float16 half4v __attribute__((ext_vector_type(4)));
typedef float floatx4 __attribute__((ext_vector_type(4)));

// Async global->LDS, 16B per lane. LDS dest is wave-uniform base + lane*16,
// so the LDS layout must be linear in thread order (it is: thread t owns
// elements [t*8, t*8+8) of the tile).
__device__ __forceinline__ void async_copy16(const _Float16* g, _Float16* l) {
    __builtin_amdgcn_global_load_lds(
        (const __attribute__((address_space(1))) void*)g,
        (__attribute__((address_space(3))) void*)l,
        16, 0, 0);
}

// C[i,j] = sum_k A[i,k] * B[j,k]   ("bt" layout: both operands row-major along K)
// QUANT=true: epilogue quantizes to nearest codebook entry, writes f16 codes.
// QUANT=false: writes fp32 accumulator to C.
template <bool QUANT>
__global__ void gemm_bt(const _Float16* __restrict__ A,
                        const _Float16* __restrict__ B,
                        const float* __restrict__ cb,
                        _Float16* __restrict__ Yq,
                        float* __restrict__ C)
{
    __shared__ _Float16 As[BM * BK];   // [row 0..127][k 0..31], no padding (global_load_lds needs linear order)
    __shared__ _Float16 Bs[BN * BK];
    __shared__ float    s_bnd[15];
    __shared__ _Float16 s_cb[16];

    const int t    = threadIdx.x;       // 256 threads = 4 waves
    const int lane = t & 63;
    const int wid  = t >> 6;
    const int wm   = (wid >> 1) * 64;   // wave tile origin within 128x128 block tile
    const int wn   = (wid & 1) * 64;
    const int bm   = blockIdx.x * BM;
    const int bn   = blockIdx.y * BN;

    if (QUANT) {
        if (t < 16) s_cb[t]  = (_Float16)cb[t];
        if (t < 15) s_bnd[t] = 0.5f * (cb[t] + cb[t + 1]);
    }

    // staging: thread t loads 16B = 8 halves; row = t/4, k-offset = (t%4)*8
    const int sr = t >> 2;
    const int sc = (t & 3) * 8;
    const _Float16* ga = A + (size_t)(bm + sr) * DIM + sc;
    const _Float16* gb = B + (size_t)(bn + sr) * DIM + sc;
    _Float16* lA = As + t * 8;
    _Float16* lB = Bs + t * 8;

    // MFMA fragment addressing (16x16x32 f16):
    // A[m=lane&15][k=(lane>>4)*8 + j], B[n=lane&15][k=(lane>>4)*8 + j]
    const int frow = lane & 15;
    const int ko   = (lane >> 4) * 8;

    floatx4 acc[4][4] = {};

    for (int k0 = 0; k0 < DIM; k0 += BK) {
        async_copy16(ga + k0,            lA);
        async_copy16(ga + k0 + 64 * DIM, lA + 64 * BK);
        async_copy16(gb + k0,            lB);
        async_copy16(gb + k0 + 64 * DIM, lB + 64 * BK);
        __syncthreads();

        half8 aF[4], bF[4];
#pragma unroll
        for (int i = 0; i < 4; ++i) {
            aF[i] = *(const half8*)&As[(wm + i * 16 + frow) * BK + ko];
            bF[i] = *(const half8*)&Bs[(wn + i * 16 + frow) * BK + ko];
        }
#pragma unroll
        for (int i = 0; i < 4; ++i)
#pragma unroll
            for (int j = 0; j < 4; ++j)
                acc[i][j] = __builtin_amdgcn_mfma_f32_16x16x32_f16(aF[i], bF[j], acc[i][j], 0, 0, 0);
        __syncthreads();
    }

    // D layout: col = lane&15, row = (lane>>4)*4 + reg  [m89-verified]
    if (QUANT) {
        float bnd[15];
#pragma unroll
        for (int b = 0; b < 15; ++b) bnd[b] = s_bnd[b];
#pragma unroll
        for (int i = 0; i < 4; ++i) {
            const int gr0 = bm + wm + i * 16 + (lane >> 4) * 4;
#pragma unroll
            for (int j = 0; j < 4; ++j) {
                const int gc = bn + wn + j * 16 + (lane & 15);
#pragma unroll
                for (int rr = 0; rr < 4; ++rr) {
                    const float v = acc[i][j][rr];
                    int idx = 0;
#pragma unroll
                    for (int b = 0; b < 15; ++b) idx += (v > bnd[b]) ? 1 : 0;
                    Yq[(size_t)(gr0 + rr) * DIM + gc] = s_cb[idx];
                }
            }
        }
    } else {
#pragma unroll
        for (int i = 0; i < 4; ++i) {
            const int gr0 = bm + wm + i * 16 + (lane >> 4) * 4;
#pragma unroll
            for (int j = 0; j < 4; ++j) {
                const int gc = bn + wn + j * 16 + (lane & 15);
#pragma unroll
                for (int rr = 0; rr < 4; ++rr)
                    C[(size_t)(gr0 + rr) * DIM + gc] = acc[i][j][rr];
            }
        }
    }
}

// x (fp32) -> f16, 4 elements/thread
__global__ void convert_f16(const float* __restrict__ in, _Float16* __restrict__ out)
{
    const size_t i = ((size_t)blockIdx.x * 256 + threadIdx.x) * 4;
    const float4 v = *(const float4*)(in + i);
    half4v h;
    h.x = (_Float16)v.x; h.y = (_Float16)v.y; h.z = (_Float16)v.z; h.w = (_Float16)v.w;
    *(half4v*)(out + i) = h;
}

// Pi (fp32) -> Pi_f16 (straight) and PiT_f16 (transposed), 32x32 LDS tiles
__global__ void prep_pi(const float* __restrict__ Pi,
                        _Float16* __restrict__ Pif,
                        _Float16* __restrict__ PiT)
{
    __shared__ _Float16 tile[32][33];
    const int tx = threadIdx.x;   // 32
    const int ty = threadIdx.y;   // 8
    const int x0 = blockIdx.x * 32;
    const int y0 = blockIdx.y * 32;
#pragma unroll
    for (int i = ty; i < 32; i += 8) {
        const float v = Pi[(size_t)(y0 + i) * DIM + x0 + tx];
        const _Float16 h = (_Float16)v;
        Pif[(size_t)(y0 + i) * DIM + x0 + tx] = h;
        tile[i][tx] = h;
    }
    __syncthreads();
#pragma unroll
    for (int i = ty; i < 32; i += 8)
        PiT[(size_t)(x0 + i) * DIM + y0 + tx] = tile[tx][i];
}

extern "C" void kernel_launch(void* const* d_in, const int* in_sizes, int n_in,
                              void* d_out, int out_size, void* d_ws, size_t ws_size,
                              hipStream_t stream)
{
    (void)in_sizes; (void)n_in; (void)out_size; (void)ws_size;
    const float* x  = (const float*)d_in[0];
    const float* Pi = (const float*)d_in[1];
    const float* cb = (const float*)d_in[2];
    float* out = (float*)d_out;

    char* ws = (char*)d_ws;
    const size_t MB32 = (size_t)DIM * DIM * sizeof(_Float16);  // 32 MiB
    _Float16* xh  = (_Float16*)(ws);
    _Float16* pih = (_Float16*)(ws + MB32);
    _Float16* pit = (_Float16*)(ws + 2 * MB32);
    _Float16* yh  = (_Float16*)(ws + 3 * MB32);

    convert_f16<<<dim3(DIM * DIM / (256 * 4)), dim3(256), 0, stream>>>(x, xh);
    prep_pi<<<dim3(DIM / 32, DIM / 32), dim3(32, 8), 0, stream>>>(Pi, pih, pit);

    // GEMM1: y = x @ Pi^T, fused Lloyd-Max quantize -> y_tilde (f16)
    gemm_bt<true><<<dim3(DIM / BM, DIM / BN), dim3(256), 0, stream>>>(xh, pih, cb, yh, nullptr);
    // GEMM2: x_tilde = y_tilde @ Pi  ==  "bt" GEMM against PiT
    gemm_bt<false><<<dim3(DIM / BM, DIM / BN), dim3(256), 0, stream>>>(yh, pit, cb, nullptr, out);
}